// Round 1
// baseline (23.079 us; speedup 1.0000x reference)
//
#include <hip/hip_runtime.h>

#define N_USERS 6040

// Each thread processes 2 batch elements:
//   load int4  (user0, movie0, user1, movie1)  -> 16 B coalesced
//   gather W[user] + W[N_USERS+movie] (+bias), sigmoid
//   store float4 (1-p0, p0, 1-p1, p1)          -> 16 B coalesced
__global__ void __launch_bounds__(256) LR_23029614641373_kernel(
    const int* __restrict__ x, const float* __restrict__ W,
    const float* __restrict__ b, float* __restrict__ out, int n_pairs) {
    int i = blockIdx.x * blockDim.x + threadIdx.x;  // pair index
    if (i >= n_pairs) return;
    float bias = b[0];
    int4 xv = *reinterpret_cast<const int4*>(x + (size_t)i * 4);
    float l0 = W[xv.x] + W[N_USERS + xv.y] + bias;
    float l1 = W[xv.z] + W[N_USERS + xv.w] + bias;
    float p0 = 1.0f / (1.0f + __expf(-l0));
    float p1 = 1.0f / (1.0f + __expf(-l1));
    float4 o = make_float4(1.0f - p0, p0, 1.0f - p1, p1);
    *reinterpret_cast<float4*>(out + (size_t)i * 4) = o;
}

extern "C" void kernel_launch(void* const* d_in, const int* in_sizes, int n_in,
                              void* d_out, int out_size, void* d_ws, size_t ws_size,
                              hipStream_t stream) {
    const int*   x = (const int*)d_in[0];    // [B, 2] int32
    const float* W = (const float*)d_in[1];  // [1, 9923] float32
    const float* b = (const float*)d_in[2];  // [1] float32
    float* out = (float*)d_out;              // [B, 2] float32

    int B = in_sizes[0] / 2;                 // 4194304
    int n_pairs = B / 2;                     // 2 batch elems per thread
    int block = 256;
    int grid = (n_pairs + block - 1) / block;
    LR_23029614641373_kernel<<<grid, block, 0, stream>>>(x, W, b, out, n_pairs);
}

// Round 2
// 18.379 us; speedup vs baseline: 1.2557x; 1.2557x over previous
//
#include <hip/hip_runtime.h>

#define N_USERS 6040
#define N_TOT   9923   // 6040 users + 3883 movies
#define BLOCK   256

// W (39.7 KB) staged in LDS; random gathers become ds_read_b32 instead of
// L1-scattered global loads. Grid-stride: 1024 blocks (4/CU at 39KB LDS),
// each thread handles 8 pairs = 16 batch elements.
__global__ void __launch_bounds__(BLOCK) LR_23029614641373_kernel(
    const int* __restrict__ x, const float* __restrict__ W,
    const float* __restrict__ b, float* __restrict__ out, int n_pairs) {
    __shared__ float w[N_TOT];
    // cooperative coalesced table load (one-time per block, L2-resident)
    for (int j = threadIdx.x; j < N_TOT; j += BLOCK) w[j] = W[j];
    float bias = b[0];
    __syncthreads();

    int stride = gridDim.x * BLOCK;
    for (int i = blockIdx.x * BLOCK + threadIdx.x; i < n_pairs; i += stride) {
        int4 xv = *reinterpret_cast<const int4*>(x + (size_t)i * 4);
        float l0 = w[xv.x] + w[N_USERS + xv.y] + bias;
        float l1 = w[xv.z] + w[N_USERS + xv.w] + bias;
        float p0 = 1.0f / (1.0f + __expf(-l0));
        float p1 = 1.0f / (1.0f + __expf(-l1));
        *reinterpret_cast<float4*>(out + (size_t)i * 4) =
            make_float4(1.0f - p0, p0, 1.0f - p1, p1);
    }
}

extern "C" void kernel_launch(void* const* d_in, const int* in_sizes, int n_in,
                              void* d_out, int out_size, void* d_ws, size_t ws_size,
                              hipStream_t stream) {
    const int*   x = (const int*)d_in[0];    // [B, 2] int32
    const float* W = (const float*)d_in[1];  // [1, 9923] float32
    const float* b = (const float*)d_in[2];  // [1] float32
    float* out = (float*)d_out;              // [B, 2] float32

    int B = in_sizes[0] / 2;                 // 4194304
    int n_pairs = B / 2;                     // 2 batch elems per thread-iter
    int grid = 1024;                         // 4 blocks/CU (LDS-limited), grid-stride x8
    LR_23029614641373_kernel<<<grid, BLOCK, 0, stream>>>(x, W, b, out, n_pairs);
}

// Round 3
// 17.669 us; speedup vs baseline: 1.3062x; 1.0402x over previous
//
#include <hip/hip_runtime.h>

#define N_USERS 6040
#define N_TOT   9923   // 6040 users + 3883 movies
#define BLOCK   512
#define GRID    1024   // 4 blocks/CU x 256 CU; LDS 4x39.7KB = 159KB/CU
#define PAIRS_PER_THREAD 4

// W (39.7 KB) in LDS. 512-thr blocks -> 32 waves/CU (100% occupancy).
// Each thread: issue 4 independent int4 x-loads FIRST (latency hides under
// table staging), then stage W via float4, sync, gather+sigmoid+store.
__global__ void __launch_bounds__(BLOCK) LR_23029614641373_kernel(
    const int* __restrict__ x, const float* __restrict__ W,
    const float* __restrict__ b, float* __restrict__ out, int n_pairs) {
    __shared__ float w[N_TOT];

    int tid = threadIdx.x;
    int i0 = blockIdx.x * BLOCK + tid;
    const int stride = GRID * BLOCK;

    // 1) issue all x loads up front (independent, 64B/lane in flight)
    int4 xv[PAIRS_PER_THREAD];
#pragma unroll
    for (int k = 0; k < PAIRS_PER_THREAD; ++k)
        xv[k] = *reinterpret_cast<const int4*>(x + (size_t)(i0 + k * stride) * 4);

    // 2) stage table: 9920 floats as float4, tail of 3 scalars
    const float4* W4 = reinterpret_cast<const float4*>(W);
    for (int j = tid; j < N_TOT / 4; j += BLOCK)
        *reinterpret_cast<float4*>(&w[j * 4]) = W4[j];
    if (tid < 3) w[9920 + tid] = W[9920 + tid];
    float bias = b[0];
    __syncthreads();

    // 3) gather + sigmoid + store
#pragma unroll
    for (int k = 0; k < PAIRS_PER_THREAD; ++k) {
        int i = i0 + k * stride;
        float l0 = w[xv[k].x] + w[N_USERS + xv[k].y] + bias;
        float l1 = w[xv[k].z] + w[N_USERS + xv[k].w] + bias;
        float p0 = 1.0f / (1.0f + __expf(-l0));
        float p1 = 1.0f / (1.0f + __expf(-l1));
        *reinterpret_cast<float4*>(out + (size_t)i * 4) =
            make_float4(1.0f - p0, p0, 1.0f - p1, p1);
    }
}

extern "C" void kernel_launch(void* const* d_in, const int* in_sizes, int n_in,
                              void* d_out, int out_size, void* d_ws, size_t ws_size,
                              hipStream_t stream) {
    const int*   x = (const int*)d_in[0];    // [B, 2] int32
    const float* W = (const float*)d_in[1];  // [1, 9923] float32
    const float* b = (const float*)d_in[2];  // [1] float32
    float* out = (float*)d_out;              // [B, 2] float32

    int B = in_sizes[0] / 2;                 // 4194304
    int n_pairs = B / 2;                     // 2097152 = GRID*BLOCK*4 exactly
    LR_23029614641373_kernel<<<GRID, BLOCK, 0, stream>>>(x, W, b, out, n_pairs);
}